// Round 1
// baseline (2339.803 us; speedup 1.0000x reference)
//
#include <hip/hip_runtime.h>
#include <hip/hip_bf16.h>
#include <math.h>

// Problem constants (from reference): R=8 relations, N=300000 nodes,
// D=128 embed dim, A=64 hidden units.
#define RR 8
#define NN 300000
#define DD 128
#define AA 64

// ---------------------------------------------------------------------------
// Kernel A: scores[r][n] = sigmoid(h[r,n,:] @ w1[r]) @ w2[r]
// grid = (ceil(N/64), R), block = 256.
// LDS: 64-node h tile (pitch 132 floats to break bank-stride-128) = 33 KB
//      + full w1_r [128][64] = 32 KB  -> 66.5 KB -> 2 blocks/CU (8 waves).
// Thread tile: 2 nodes x 8 units, k vectorized by 4 (float4 LDS reads).
// Per k4 step: 10x ds_read_b128 (~120 cyc) vs 64 v_fma (~128 cyc) -> VALU-bound.
// ---------------------------------------------------------------------------
#define HS_PITCH 132  // 128 + 4 pad: node stride 264 floats = 8 banks mod 32 -> 2-way (free)

__global__ __launch_bounds__(256, 2) void score_kernel(
    const float* __restrict__ h, const float* __restrict__ w1,
    const float* __restrict__ w2, float* __restrict__ scores) {
  __shared__ float h_s[64 * HS_PITCH];   // [node][d], padded pitch
  __shared__ float w1_s[DD * AA];        // [k][a], a contiguous (row 64 floats)

  const int t = threadIdx.x;
  const int r = blockIdx.y;
  const int n0 = blockIdx.x * 64;

  // ---- stage h tile: 64 nodes x 128 d = 2048 float4, 8 per thread, coalesced
  {
    const float* hr = h + (size_t)r * NN * DD;
#pragma unroll
    for (int i = 0; i < 8; ++i) {
      int idx = t + i * 256;           // 0..2047
      int n = idx >> 5;                // node-local
      int d4 = (idx & 31) * 4;         // d offset
      float4 v = make_float4(0.f, 0.f, 0.f, 0.f);
      if (n0 + n < NN) v = *(const float4*)(hr + (size_t)(n0 + n) * DD + d4);
      *(float4*)(&h_s[n * HS_PITCH + d4]) = v;
    }
  }
  // ---- stage w1_r: 8192 floats = 2048 float4, coalesced, natural [d][a] layout
  {
    const float* w1r = w1 + (size_t)r * DD * AA;
#pragma unroll
    for (int i = 0; i < 8; ++i) {
      int idx = (t + i * 256) * 4;
      *(float4*)(&w1_s[idx]) = *(const float4*)(w1r + idx);
    }
  }
  __syncthreads();

  const int uslot = t & 7;    // unit group: a0 = uslot*8 (lanes w/ same nslot broadcast h)
  const int nslot = t >> 3;   // 0..31 -> nodes 2*nslot, 2*nslot+1
  const int a0 = uslot * 8;
  const int nA = nslot * 2;
  const int nB = nA + 1;

  float acc0[8], acc1[8];
#pragma unroll
  for (int j = 0; j < 8; ++j) { acc0[j] = 0.f; acc1[j] = 0.f; }

  const float* hA = &h_s[nA * HS_PITCH];
  const float* hB = &h_s[nB * HS_PITCH];

#pragma unroll 4
  for (int k4 = 0; k4 < 32; ++k4) {
    const int k = k4 * 4;
    float4 ha = *(const float4*)(hA + k);
    float4 hb = *(const float4*)(hB + k);
#pragma unroll
    for (int dk = 0; dk < 4; ++dk) {
      const float* wrow = &w1_s[(k + dk) * AA + a0];
      float4 w0 = *(const float4*)(wrow);
      float4 w1v = *(const float4*)(wrow + 4);
      float xa = ((const float*)&ha)[dk];
      float xb = ((const float*)&hb)[dk];
      acc0[0] = fmaf(xa, w0.x, acc0[0]);
      acc0[1] = fmaf(xa, w0.y, acc0[1]);
      acc0[2] = fmaf(xa, w0.z, acc0[2]);
      acc0[3] = fmaf(xa, w0.w, acc0[3]);
      acc0[4] = fmaf(xa, w1v.x, acc0[4]);
      acc0[5] = fmaf(xa, w1v.y, acc0[5]);
      acc0[6] = fmaf(xa, w1v.z, acc0[6]);
      acc0[7] = fmaf(xa, w1v.w, acc0[7]);
      acc1[0] = fmaf(xb, w0.x, acc1[0]);
      acc1[1] = fmaf(xb, w0.y, acc1[1]);
      acc1[2] = fmaf(xb, w0.z, acc1[2]);
      acc1[3] = fmaf(xb, w0.w, acc1[3]);
      acc1[4] = fmaf(xb, w1v.x, acc1[4]);
      acc1[5] = fmaf(xb, w1v.y, acc1[5]);
      acc1[6] = fmaf(xb, w1v.z, acc1[6]);
      acc1[7] = fmaf(xb, w1v.w, acc1[7]);
    }
  }

  // hidden = sigmoid(acc); partial score = sum_j sigmoid * w2[a0+j]
  const float* w2r = w2 + r * AA + a0;
  float4 w2a = *(const float4*)(w2r);
  float4 w2b = *(const float4*)(w2r + 4);
  float wv[8] = {w2a.x, w2a.y, w2a.z, w2a.w, w2b.x, w2b.y, w2b.z, w2b.w};
  float pA = 0.f, pB = 0.f;
#pragma unroll
  for (int j = 0; j < 8; ++j) {
    pA += wv[j] * (1.f / (1.f + __expf(-acc0[j])));
    pB += wv[j] * (1.f / (1.f + __expf(-acc1[j])));
  }
  // reduce over uslot (low 3 lane bits) via butterfly shuffle
  pA += __shfl_xor(pA, 1); pA += __shfl_xor(pA, 2); pA += __shfl_xor(pA, 4);
  pB += __shfl_xor(pB, 1); pB += __shfl_xor(pB, 2); pB += __shfl_xor(pB, 4);

  if (uslot == 0) {
    if (n0 + nA < NN) scores[(size_t)r * NN + n0 + nA] = pA;
    if (n0 + nB < NN) scores[(size_t)r * NN + n0 + nB] = pB;
  }
}

// ---------------------------------------------------------------------------
// Kernel B: out[n,:] = sum_r softmax_r(scores[:,n]) * h[r,n,:]
// Pure streaming: thread = (node, d-float4). grid = N/8, block 256
// (8 nodes x 32 float4 per block). 1.23 GB read + 154 MB write -> HBM-bound.
// ---------------------------------------------------------------------------
__global__ __launch_bounds__(256) void out_kernel(
    const float* __restrict__ h, const float* __restrict__ scores,
    float* __restrict__ out) {
  const int t = threadIdx.x;
  const int n = blockIdx.x * 8 + (t >> 5);
  const int d4 = (t & 31) * 4;
  if (n >= NN) return;

  float s[RR];
#pragma unroll
  for (int r = 0; r < RR; ++r) s[r] = scores[(size_t)r * NN + n];
  float m = s[0];
#pragma unroll
  for (int r = 1; r < RR; ++r) m = fmaxf(m, s[r]);
  float e[RR], sum = 0.f;
#pragma unroll
  for (int r = 0; r < RR; ++r) { e[r] = __expf(s[r] - m); sum += e[r]; }
  const float inv = 1.f / sum;

  float4 o = make_float4(0.f, 0.f, 0.f, 0.f);
#pragma unroll
  for (int r = 0; r < RR; ++r) {
    float4 hv = *(const float4*)(h + ((size_t)r * NN + n) * DD + d4);
    float a = e[r] * inv;
    o.x = fmaf(a, hv.x, o.x);
    o.y = fmaf(a, hv.y, o.y);
    o.z = fmaf(a, hv.z, o.z);
    o.w = fmaf(a, hv.w, o.w);
  }
  *(float4*)(out + (size_t)n * DD + d4) = o;
}

extern "C" void kernel_launch(void* const* d_in, const int* in_sizes, int n_in,
                              void* d_out, int out_size, void* d_ws, size_t ws_size,
                              hipStream_t stream) {
  const float* h  = (const float*)d_in[0];   // [R, N, D]
  const float* w1 = (const float*)d_in[1];   // [R, D, A]
  const float* w2 = (const float*)d_in[2];   // [R, A, 1]
  float* out = (float*)d_out;                // [N, D]
  float* scores = (float*)d_ws;              // [R, N] scratch, 9.6 MB

  dim3 gA((NN + 63) / 64, RR);
  score_kernel<<<gA, 256, 0, stream>>>(h, w1, w2, scores);
  out_kernel<<<(NN + 7) / 8, 256, 0, stream>>>(h, scores, out);
}